// Round 1
// baseline (302.572 us; speedup 1.0000x reference)
//
#include <hip/hip_runtime.h>
#include <hip/hip_bf16.h>

// C[M,N] = A[M,K] @ B[N,K]^T, fp32 in/out, bf16 MFMA.
// Phase 1: one fused fp32->bf16 convert kernel for A and B into d_ws.
// Phase 2: 256x128/BK=64 GEMM, 512 thr (8 waves 4Mx2N, 64x64/wave),
//   3-buffer LDS ring (144 KiB) with depth-2 global_load_lds prefetch:
//   tile t's phases issue tile t+2's 6 loads; tile boundary waits
//   s_waitcnt vmcnt(6) (counted, never 0 in steady state) + raw s_barrier.
//   4 phases/tile: {ds_read subtile | stage issue; bar; setprio(1); 8 MFMA;
//   setprio(0); bar}. XOR bank-swizzle on 16B chunks carried over from the
//   verified 128^2 kernel (slot(c,row)=c^(row&7); staging lane fetches
//   global chunk (lane&7)^(row&7) so HW's base+lane*16 placement lands
//   swizzled; frag read slot ((qd+4c)^(fr&7)) -> conflict-free, measured 0).
//   XCD-bijective block swizzle: each XCD gets a 4bm x 8bn chunk.

typedef __bf16 bf16x8 __attribute__((ext_vector_type(8)));
typedef float f32x4 __attribute__((ext_vector_type(4)));

#define BM 256
#define BN 128
#define BK 64
#define NBUF 3
// fallback tile
#define TM 128
#define TN 128

#define MFMA16(a_, b_, c_) \
    __builtin_amdgcn_mfma_f32_16x16x32_bf16((a_), (b_), (c_), 0, 0, 0)

__device__ __forceinline__ void load_lds16(const void* g, void* l) {
    __builtin_amdgcn_global_load_lds(
        (const __attribute__((address_space(1))) void*)g,
        (__attribute__((address_space(3))) void*)l,
        16 /*bytes*/, 0 /*offset*/, 0 /*aux*/);
}

// ---- fused convert: A then B, grid-stride. nA8 = aN/8 is an exact multiple
// of 2048*256 so the A/B split never diverges within an iteration.
__global__ void cvt_all(const float* __restrict__ A, uint4* __restrict__ Ao,
                        long nA8, const float* __restrict__ B,
                        uint4* __restrict__ Bo, long nB8) {
    const long stride = (long)gridDim.x * blockDim.x;
    const long tot = nA8 + nB8;
    for (long i = (long)blockIdx.x * blockDim.x + threadIdx.x; i < tot;
         i += stride) {
        const float4* p;
        uint4* d;
        if (i < nA8) {
            p = (const float4*)A + i * 2;
            d = Ao + i;
        } else {
            const long j = i - nA8;
            p = (const float4*)B + j * 2;
            d = Bo + j;
        }
        const float4 a = p[0];
        const float4 b = p[1];
        union { __hip_bfloat16 h[8]; uint4 u; } o;
        o.h[0] = __float2bfloat16(a.x); o.h[1] = __float2bfloat16(a.y);
        o.h[2] = __float2bfloat16(a.z); o.h[3] = __float2bfloat16(a.w);
        o.h[4] = __float2bfloat16(b.x); o.h[5] = __float2bfloat16(b.y);
        o.h[6] = __float2bfloat16(b.z); o.h[7] = __float2bfloat16(b.w);
        *d = o.u;
    }
}

// fragment read: row = w? + idx*16 + fr, chunk (qd+4c) at swizzled slot
#define RD_A(c_, i_)                                                          \
    (*(const bf16x8*)(as + (wm + (i_) * 16 + fr) * BK +                       \
                      ((((qd) + 4 * (c_)) ^ r7) << 3)))
#define RD_B(c_, j_)                                                          \
    (*(const bf16x8*)(bs + (wn + (j_) * 16 + fr) * BK +                       \
                      ((((qd) + 4 * (c_)) ^ r7) << 3)))

__global__ __launch_bounds__(512, 2) void gemm_bt_pipe(
    const __bf16* __restrict__ A,  // [M,K] bf16
    const __bf16* __restrict__ B,  // [N,K] bf16
    float* __restrict__ C,         // [M,N] fp32
    int M, int N, int K) {
    __shared__ __bf16 As[NBUF * BM * BK];  // 96 KiB
    __shared__ __bf16 Bs[NBUF * BN * BK];  // 48 KiB

    const int tid = threadIdx.x;
    const int wave = tid >> 6;
    const int lane = tid & 63;

    // ---- XCD-bijective swizzle: XCD x (= launchID%8 under round-robin)
    // owns blocks (bm in [4x,4x+4), all bn) -> per-XCD working set
    // A 8MB + B 8MB instead of full-A per XCD.
    const int nbn = N / BN;  // 8
    const int nbm = M / BM;  // 32
    const int L = (int)blockIdx.x;
    int bm, bn;
    if ((nbm & 7) == 0) {
        const int x = L & 7;
        const int s = L >> 3;
        bm = x * (nbm >> 3) + s / nbn;
        bn = s % nbn;
    } else {
        bm = L / nbn;
        bn = L % nbn;
    }

    // ---- staging: row = 128 B = 8 chunks; 512 threads cover 64 rows/round.
    // A tile = 4 rounds, B tile = 2 rounds; 6 loads/thread/K-tile.
    const int srow = tid >> 3;                    // row within round (0..63)
    const int schk = (tid & 7) ^ (srow & 7);      // pre-swizzled global chunk
    const __bf16* ga = A + ((size_t)bm * BM + srow) * (size_t)K + schk * 8;
    const __bf16* gb = B + ((size_t)bn * BN + srow) * (size_t)K + schk * 8;
    const size_t g64 = (size_t)64 * K;            // 64-row advance per round
    const int ldst = tid * 8;                     // LDS elem offset in round

    // ---- fragment addressing (identical math to the verified 128^2 kernel)
    const int wm = (wave >> 1) << 6;  // 0,64,128,192
    const int wn = (wave & 1) << 6;   // 0,64
    const int fr = lane & 15;
    const int qd = lane >> 4;
    const int r7 = fr & 7;

    f32x4 acc[4][4];
#pragma unroll
    for (int i = 0; i < 4; ++i)
#pragma unroll
        for (int j = 0; j < 4; ++j) acc[i][j] = (f32x4){0.f, 0.f, 0.f, 0.f};

    const int NT = K / BK;  // 64

    // ---- prologue: stage tiles 0 and 1 (6 loads each, tile-ordered)
#pragma unroll
    for (int r = 0; r < 4; ++r) load_lds16(ga + r * g64, As + ldst + r * 4096);
#pragma unroll
    for (int r = 0; r < 2; ++r) load_lds16(gb + r * g64, Bs + ldst + r * 4096);
    asm volatile("" ::: "memory");
#pragma unroll
    for (int r = 0; r < 4; ++r)
        load_lds16(ga + r * g64 + BK, As + BM * BK + ldst + r * 4096);
#pragma unroll
    for (int r = 0; r < 2; ++r)
        load_lds16(gb + r * g64 + BK, Bs + BN * BK + ldst + r * 4096);
    asm volatile("s_waitcnt vmcnt(6)" ::: "memory");  // tile 0 resident
    __builtin_amdgcn_s_barrier();
    asm volatile("" ::: "memory");

    int cur = 0, nx = 2;
    for (int t = 0; t < NT; ++t) {
        const __bf16* as = As + cur * (BM * BK);
        const __bf16* bs = Bs + cur * (BN * BK);
        __bf16* asw = As + nx * (BM * BK);
        __bf16* bsw = Bs + nx * (BN * BK);
        const bool pf = (t + 2 < NT);
        const size_t kg = (size_t)(t + 2) * BK;

        bf16x8 af[2][4], bf[2][4];

        // ---------- phase 0: c=0 B all + A i=0,1 | stage A rounds 0-1
#pragma unroll
        for (int j = 0; j < 4; ++j) bf[0][j] = RD_B(0, j);
        af[0][0] = RD_A(0, 0);
        af[0][1] = RD_A(0, 1);
        if (pf) {
            load_lds16(ga + 0 * g64 + kg, asw + ldst);
            load_lds16(ga + 1 * g64 + kg, asw + ldst + 4096);
        }
        asm volatile("" ::: "memory");
        __builtin_amdgcn_s_barrier();
        __builtin_amdgcn_s_setprio(1);
#pragma unroll
        for (int i = 0; i < 2; ++i)
#pragma unroll
            for (int j = 0; j < 4; ++j)
                acc[i][j] = MFMA16(af[0][i], bf[0][j], acc[i][j]);
        __builtin_amdgcn_s_setprio(0);
        __builtin_amdgcn_s_barrier();

        // ---------- phase 1: c=0 A i=2,3 | stage A rounds 2-3
        af[0][2] = RD_A(0, 2);
        af[0][3] = RD_A(0, 3);
        if (pf) {
            load_lds16(ga + 2 * g64 + kg, asw + ldst + 2 * 4096);
            load_lds16(ga + 3 * g64 + kg, asw + ldst + 3 * 4096);
        }
        asm volatile("" ::: "memory");
        __builtin_amdgcn_s_barrier();
        __builtin_amdgcn_s_setprio(1);
#pragma unroll
        for (int i = 2; i < 4; ++i)
#pragma unroll
            for (int j = 0; j < 4; ++j)
                acc[i][j] = MFMA16(af[0][i], bf[0][j], acc[i][j]);
        __builtin_amdgcn_s_setprio(0);
        __builtin_amdgcn_s_barrier();

        // ---------- phase 2: c=1 B all + A i=0,1 | stage B round 0
#pragma unroll
        for (int j = 0; j < 4; ++j) bf[1][j] = RD_B(1, j);
        af[1][0] = RD_A(1, 0);
        af[1][1] = RD_A(1, 1);
        if (pf) load_lds16(gb + 0 * g64 + kg, bsw + ldst);
        asm volatile("" ::: "memory");
        __builtin_amdgcn_s_barrier();
        __builtin_amdgcn_s_setprio(1);
#pragma unroll
        for (int i = 0; i < 2; ++i)
#pragma unroll
            for (int j = 0; j < 4; ++j)
                acc[i][j] = MFMA16(af[1][i], bf[1][j], acc[i][j]);
        __builtin_amdgcn_s_setprio(0);
        __builtin_amdgcn_s_barrier();

        // ---------- phase 3: c=1 A i=2,3 | stage B round 1 | tile boundary
        af[1][2] = RD_A(1, 2);
        af[1][3] = RD_A(1, 3);
        if (pf) load_lds16(gb + 1 * g64 + kg, bsw + ldst + 4096);
        asm volatile("" ::: "memory");
        __builtin_amdgcn_s_barrier();
        __builtin_amdgcn_s_setprio(1);
#pragma unroll
        for (int i = 2; i < 4; ++i)
#pragma unroll
            for (int j = 0; j < 4; ++j)
                acc[i][j] = MFMA16(af[1][i], bf[1][j], acc[i][j]);
        __builtin_amdgcn_s_setprio(0);
        if (t + 1 < NT) {
            // counted wait: allow tile t+2's 6 loads to stay in flight;
            // guarantees tile t+1 (the 6 oldest) landed. Tail drains to 0.
            if (pf) asm volatile("s_waitcnt vmcnt(6)" ::: "memory");
            else    asm volatile("s_waitcnt vmcnt(0)" ::: "memory");
            __builtin_amdgcn_s_barrier();
            asm volatile("" ::: "memory");
        }
        cur = (cur == NBUF - 1) ? 0 : cur + 1;
        nx = (nx == NBUF - 1) ? 0 : nx + 1;
    }

    // ---- epilogue: C/D layout col=lane&15, row=(lane>>4)*4+reg  [m89/m91]
    const int cq = qd << 2;
    float* Cbase = C + ((size_t)bm * BM + wm + cq) * (size_t)N +
                   (size_t)bn * BN + wn + fr;
#pragma unroll
    for (int i = 0; i < 4; ++i)
#pragma unroll
        for (int r = 0; r < 4; ++r) {
            float* row = Cbase + (size_t)(16 * i + r) * N;
#pragma unroll
            for (int j = 0; j < 4; ++j) row[16 * j] = acc[i][j][r];
        }
}

// Fallback if ws too small: fused-convert GEMM (BK=32), plain stores.
__global__ __launch_bounds__(256, 2) void gemm_bt_f32in(
    const float* __restrict__ A, const float* __restrict__ B,
    float* __restrict__ C, int M, int N, int K) {
    __shared__ __bf16 As[TM * 32];
    __shared__ __bf16 Bs[TN * 32];

    const int tid = threadIdx.x;
    const int wave = tid >> 6;
    const int lane = tid & 63;
    const int bn = blockIdx.x;
    const int bm = blockIdx.y;

    const int frow = tid >> 3;
    const int fcol = (tid & 7) << 2;
    const float* gaf = A + ((size_t)bm * TM + frow) * (size_t)K + fcol;
    const float* gbf = B + ((size_t)bn * TN + frow) * (size_t)K + fcol;

    const int wm = (wave >> 1) << 6;
    const int wn = (wave & 1) << 6;
    const int fr = lane & 15;
    const int fk = (lane >> 4) << 3;
    const __bf16* pa = As + (wm + fr) * 32 + fk;
    const __bf16* pb = Bs + (wn + fr) * 32 + fk;

    f32x4 acc[4][4];
#pragma unroll
    for (int i = 0; i < 4; ++i)
#pragma unroll
        for (int j = 0; j < 4; ++j) acc[i][j] = (f32x4){0.f, 0.f, 0.f, 0.f};

    for (int k0 = 0; k0 < K; k0 += 32) {
#pragma unroll
        for (int rd = 0; rd < 4; ++rd) {
            float4 va = *(const float4*)(gaf + (size_t)(rd * 32) * K + k0);
            float4 vb = *(const float4*)(gbf + (size_t)(rd * 32) * K + k0);
            union { __hip_bfloat162 h2[2]; uint2 u; } oa, ob;
            oa.h2[0] = __float22bfloat162_rn(make_float2(va.x, va.y));
            oa.h2[1] = __float22bfloat162_rn(make_float2(va.z, va.w));
            ob.h2[0] = __float22bfloat162_rn(make_float2(vb.x, vb.y));
            ob.h2[1] = __float22bfloat162_rn(make_float2(vb.z, vb.w));
            *(uint2*)(As + (frow + rd * 32) * 32 + fcol) = oa.u;
            *(uint2*)(Bs + (frow + rd * 32) * 32 + fcol) = ob.u;
        }
        __syncthreads();

        bf16x8 af[4], bfr[4];
#pragma unroll
        for (int i = 0; i < 4; ++i) af[i] = *(const bf16x8*)(pa + i * (16 * 32));
#pragma unroll
        for (int j = 0; j < 4; ++j) bfr[j] = *(const bf16x8*)(pb + j * (16 * 32));
#pragma unroll
        for (int i = 0; i < 4; ++i)
#pragma unroll
            for (int j = 0; j < 4; ++j)
                acc[i][j] = __builtin_amdgcn_mfma_f32_16x16x32_bf16(
                    af[i], bfr[j], acc[i][j], 0, 0, 0);
        __syncthreads();
    }

    const int cq = (lane >> 4) << 2;
    float* Cbase = C + ((size_t)bm * TM + wm + cq) * (size_t)N +
                   (size_t)bn * TN + wn + fr;
#pragma unroll
    for (int i = 0; i < 4; ++i)
#pragma unroll
        for (int r = 0; r < 4; ++r) {
            float* row = Cbase + (size_t)(16 * i + r) * N;
#pragma unroll
            for (int j = 0; j < 4; ++j) row[16 * j] = acc[i][j][r];
        }
}

extern "C" void kernel_launch(void* const* d_in, const int* in_sizes, int n_in,
                              void* d_out, int out_size, void* d_ws,
                              size_t ws_size, hipStream_t stream) {
    const float* A = (const float*)d_in[0];  // [M,K] (all_gather = reshape)
    const float* B = (const float*)d_in[1];  // [N,K]
    float* C = (float*)d_out;

    const int K = 4096;
    const int aN = in_sizes[0];
    const int bN = in_sizes[1];
    const int M = aN / K;  // 8192
    const int N = bN / K;  // 1024

    const size_t need = ((size_t)aN + (size_t)bN) * sizeof(__hip_bfloat16);

    if (ws_size >= need && (M % BM) == 0 && (N % BN) == 0) {
        __hip_bfloat16* Abf = (__hip_bfloat16*)d_ws;
        __hip_bfloat16* Bbf = Abf + (size_t)aN;
        cvt_all<<<2048, 256, 0, stream>>>(A, (uint4*)Abf, (long)(aN / 8), B,
                                          (uint4*)Bbf, (long)(bN / 8));
        dim3 grid((unsigned)((M / BM) * (N / BN)));  // 256 = 1 block/CU
        gemm_bt_pipe<<<grid, 512, 0, stream>>>((const __bf16*)Abf,
                                               (const __bf16*)Bbf, C, M, N, K);
    } else {
        dim3 grid(N / TN, M / TM);
        gemm_bt_f32in<<<grid, 256, 0, stream>>>(A, B, C, M, N, K);
    }
}

// Round 2
// 284.721 us; speedup vs baseline: 1.0627x; 1.0627x over previous
//
#include <hip/hip_runtime.h>
#include <hip/hip_bf16.h>

// C[M,N] = A[M,K] @ B[N,K]^T, fp32 in/out, bf16 MFMA.
// Phase 1: one fused fp32->bf16 convert kernel for A and B into d_ws.
// Phase 2: 256x128/BK=64 GEMM, 512 thr (8 waves 4Mx2N, 64x64/wave),
//   3-buffer LDS ring (144 KiB) with depth-2 global_load_lds prefetch.
//   R1 post-mortem: 4 phases x 8 MFMA with 2 barriers/phase = 8 bars/tile
//   in lockstep at 1 block/CU -> 3500 cyc/tile vs 1242 of MFMA work
//   (MfmaUtil 29%). R2: 2 phases x 16 MFMA (template cluster size), ONE
//   barrier per phase (reads+stage; bar; prio1; 16 MFMA; prio0) -> waves
//   drift ~1 phase so ds_read overlaps other waves' MFMA; 3 bars/tile.
//   Correctness fences: per-tile s_waitcnt vmcnt(6) (counted, per-wave)
//   BEFORE the boundary barrier (barrier publishes all waves' loads), and
//   an asm memory fence after it pinning next-tile ds_reads. Tail drains
//   vmcnt(0). XOR bank-swizzle on 16B chunks (slot(c,row)=c^(row&7),
//   staging lane fetches pre-swizzled global chunk; measured 0 conflicts).
//   XCD-bijective block swizzle: each XCD owns a 4bm x 8bn chunk
//   (FETCH_SIZE 266->65.6 MB, ~compulsory traffic; HBM now 13% of peak).

typedef __bf16 bf16x8 __attribute__((ext_vector_type(8)));
typedef float f32x4 __attribute__((ext_vector_type(4)));

#define BM 256
#define BN 128
#define BK 64
#define NBUF 3
// fallback tile
#define TM 128
#define TN 128

#define MFMA16(a_, b_, c_) \
    __builtin_amdgcn_mfma_f32_16x16x32_bf16((a_), (b_), (c_), 0, 0, 0)

__device__ __forceinline__ void load_lds16(const void* g, void* l) {
    __builtin_amdgcn_global_load_lds(
        (const __attribute__((address_space(1))) void*)g,
        (__attribute__((address_space(3))) void*)l,
        16 /*bytes*/, 0 /*offset*/, 0 /*aux*/);
}

// ---- fused convert: A then B, grid-stride.
__global__ void cvt_all(const float* __restrict__ A, uint4* __restrict__ Ao,
                        long nA8, const float* __restrict__ B,
                        uint4* __restrict__ Bo, long nB8) {
    const long stride = (long)gridDim.x * blockDim.x;
    const long tot = nA8 + nB8;
    for (long i = (long)blockIdx.x * blockDim.x + threadIdx.x; i < tot;
         i += stride) {
        const float4* p;
        uint4* d;
        if (i < nA8) {
            p = (const float4*)A + i * 2;
            d = Ao + i;
        } else {
            const long j = i - nA8;
            p = (const float4*)B + j * 2;
            d = Bo + j;
        }
        const float4 a = p[0];
        const float4 b = p[1];
        union { __hip_bfloat16 h[8]; uint4 u; } o;
        o.h[0] = __float2bfloat16(a.x); o.h[1] = __float2bfloat16(a.y);
        o.h[2] = __float2bfloat16(a.z); o.h[3] = __float2bfloat16(a.w);
        o.h[4] = __float2bfloat16(b.x); o.h[5] = __float2bfloat16(b.y);
        o.h[6] = __float2bfloat16(b.z); o.h[7] = __float2bfloat16(b.w);
        *d = o.u;
    }
}

// fragment read: row = w? + idx*16 + fr, chunk (qd+4c) at swizzled slot
#define RD_A(c_, i_)                                                          \
    (*(const bf16x8*)(as + (wm + (i_) * 16 + fr) * BK +                       \
                      ((((qd) + 4 * (c_)) ^ r7) << 3)))
#define RD_B(c_, j_)                                                          \
    (*(const bf16x8*)(bs + (wn + (j_) * 16 + fr) * BK +                       \
                      ((((qd) + 4 * (c_)) ^ r7) << 3)))

__global__ __launch_bounds__(512, 2) void gemm_bt_pipe(
    const __bf16* __restrict__ A,  // [M,K] bf16
    const __bf16* __restrict__ B,  // [N,K] bf16
    float* __restrict__ C,         // [M,N] fp32
    int M, int N, int K) {
    __shared__ __bf16 As[NBUF * BM * BK];  // 96 KiB
    __shared__ __bf16 Bs[NBUF * BN * BK];  // 48 KiB

    const int tid = threadIdx.x;
    const int wave = tid >> 6;
    const int lane = tid & 63;

    // ---- XCD-bijective swizzle: XCD x (= launchID%8 under round-robin)
    // owns blocks (bm in [4x,4x+4), all bn) -> per-XCD working set ~16 MB.
    const int nbn = N / BN;
    const int nbm = M / BM;
    const int L = (int)blockIdx.x;
    int bm, bn;
    if ((nbm & 7) == 0) {
        const int x = L & 7;
        const int s = L >> 3;
        bm = x * (nbm >> 3) + s / nbn;
        bn = s % nbn;
    } else {
        bm = L / nbn;
        bn = L % nbn;
    }

    // ---- staging: row = 128 B = 8 chunks; 512 threads cover 64 rows/round.
    // A tile = 4 rounds, B tile = 2 rounds; 6 loads/thread/K-tile.
    const int srow = tid >> 3;                    // row within round (0..63)
    const int schk = (tid & 7) ^ (srow & 7);      // pre-swizzled global chunk
    const __bf16* ga = A + ((size_t)bm * BM + srow) * (size_t)K + schk * 8;
    const __bf16* gb = B + ((size_t)bn * BN + srow) * (size_t)K + schk * 8;
    const size_t g64 = (size_t)64 * K;            // 64-row advance per round
    const int ldst = tid * 8;                     // LDS elem offset in round

    // ---- fragment addressing
    const int wm = (wave >> 1) << 6;  // 0,64,128,192
    const int wn = (wave & 1) << 6;   // 0,64
    const int fr = lane & 15;
    const int qd = lane >> 4;
    const int r7 = fr & 7;

    f32x4 acc[4][4];
#pragma unroll
    for (int i = 0; i < 4; ++i)
#pragma unroll
        for (int j = 0; j < 4; ++j) acc[i][j] = (f32x4){0.f, 0.f, 0.f, 0.f};

    const int NT = K / BK;  // 64

    // ---- prologue: stage tiles 0 and 1 (6 loads each, tile-ordered)
#pragma unroll
    for (int r = 0; r < 4; ++r) load_lds16(ga + r * g64, As + ldst + r * 4096);
#pragma unroll
    for (int r = 0; r < 2; ++r) load_lds16(gb + r * g64, Bs + ldst + r * 4096);
    asm volatile("" ::: "memory");
#pragma unroll
    for (int r = 0; r < 4; ++r)
        load_lds16(ga + r * g64 + BK, As + BM * BK + ldst + r * 4096);
#pragma unroll
    for (int r = 0; r < 2; ++r)
        load_lds16(gb + r * g64 + BK, Bs + BN * BK + ldst + r * 4096);
    asm volatile("s_waitcnt vmcnt(6)" ::: "memory");  // tile 0 resident
    __builtin_amdgcn_s_barrier();
    asm volatile("" ::: "memory");

    int cur = 0, nx = 2;
    for (int t = 0; t < NT; ++t) {
        const __bf16* as = As + cur * (BM * BK);
        const __bf16* bs = Bs + cur * (BN * BK);
        __bf16* asw = As + nx * (BM * BK);
        __bf16* bsw = Bs + nx * (BN * BK);
        const bool pf = (t + 2 < NT);
        const size_t kg = (size_t)(t + 2) * BK;

        bf16x8 af[2][4], bf[2][4];

        // ---------- phase 0: c=0 frags (8 ds_read) | stage A r0,r1 + B r0
#pragma unroll
        for (int j = 0; j < 4; ++j) bf[0][j] = RD_B(0, j);
#pragma unroll
        for (int i = 0; i < 4; ++i) af[0][i] = RD_A(0, i);
        if (pf) {
            load_lds16(ga + 0 * g64 + kg, asw + ldst);
            load_lds16(ga + 1 * g64 + kg, asw + ldst + 4096);
            load_lds16(gb + 0 * g64 + kg, bsw + ldst);
        }
        __builtin_amdgcn_s_barrier();
        __builtin_amdgcn_s_setprio(1);
#pragma unroll
        for (int i = 0; i < 4; ++i)
#pragma unroll
            for (int j = 0; j < 4; ++j)
                acc[i][j] = MFMA16(af[0][i], bf[0][j], acc[i][j]);
        __builtin_amdgcn_s_setprio(0);
        // no closing barrier: waves drift into phase 1's reads while others
        // finish MFMAs -> LDS pipe overlaps matrix pipe across waves.

        // ---------- phase 1: c=1 frags | stage A r2,r3 + B r1
#pragma unroll
        for (int j = 0; j < 4; ++j) bf[1][j] = RD_B(1, j);
#pragma unroll
        for (int i = 0; i < 4; ++i) af[1][i] = RD_A(1, i);
        if (pf) {
            load_lds16(ga + 2 * g64 + kg, asw + ldst + 2 * 4096);
            load_lds16(ga + 3 * g64 + kg, asw + ldst + 3 * 4096);
            load_lds16(gb + 1 * g64 + kg, bsw + ldst + 4096);
        }
        __builtin_amdgcn_s_barrier();
        __builtin_amdgcn_s_setprio(1);
#pragma unroll
        for (int i = 0; i < 4; ++i)
#pragma unroll
            for (int j = 0; j < 4; ++j)
                acc[i][j] = MFMA16(af[1][i], bf[1][j], acc[i][j]);
        __builtin_amdgcn_s_setprio(0);

        // ---------- tile boundary: counted wait (per-wave), then barrier
        // publishes ALL waves' t+1 loads; memory fence pins next-tile reads.
        if (t + 1 < NT) {
            if (pf) asm volatile("s_waitcnt vmcnt(6)" ::: "memory");
            else    asm volatile("s_waitcnt vmcnt(0)" ::: "memory");
            __builtin_amdgcn_s_barrier();
            asm volatile("" ::: "memory");
        }
        cur = (cur == NBUF - 1) ? 0 : cur + 1;
        nx = (nx == NBUF - 1) ? 0 : nx + 1;
    }

    // ---- epilogue: C/D layout col=lane&15, row=(lane>>4)*4+reg  [m89/m91]
    const int cq = qd << 2;
    float* Cbase = C + ((size_t)bm * BM + wm + cq) * (size_t)N +
                   (size_t)bn * BN + wn + fr;
#pragma unroll
    for (int i = 0; i < 4; ++i)
#pragma unroll
        for (int r = 0; r < 4; ++r) {
            float* row = Cbase + (size_t)(16 * i + r) * N;
#pragma unroll
            for (int j = 0; j < 4; ++j) row[16 * j] = acc[i][j][r];
        }
}

// Fallback if ws too small: fused-convert GEMM (BK=32), plain stores.
__global__ __launch_bounds__(256, 2) void gemm_bt_f32in(
    const float* __restrict__ A, const float* __restrict__ B,
    float* __restrict__ C, int M, int N, int K) {
    __shared__ __bf16 As[TM * 32];
    __shared__ __bf16 Bs[TN * 32];

    const int tid = threadIdx.x;
    const int wave = tid >> 6;
    const int lane = tid & 63;
    const int bn = blockIdx.x;
    const int bm = blockIdx.y;

    const int frow = tid >> 3;
    const int fcol = (tid & 7) << 2;
    const float* gaf = A + ((size_t)bm * TM + frow) * (size_t)K + fcol;
    const float* gbf = B + ((size_t)bn * TN + frow) * (size_t)K + fcol;

    const int wm = (wave >> 1) << 6;
    const int wn = (wave & 1) << 6;
    const int fr = lane & 15;
    const int fk = (lane >> 4) << 3;
    const __bf16* pa = As + (wm + fr) * 32 + fk;
    const __bf16* pb = Bs + (wn + fr) * 32 + fk;

    f32x4 acc[4][4];
#pragma unroll
    for (int i = 0; i < 4; ++i)
#pragma unroll
        for (int j = 0; j < 4; ++j) acc[i][j] = (f32x4){0.f, 0.f, 0.f, 0.f};

    for (int k0 = 0; k0 < K; k0 += 32) {
#pragma unroll
        for (int rd = 0; rd < 4; ++rd) {
            float4 va = *(const float4*)(gaf + (size_t)(rd * 32) * K + k0);
            float4 vb = *(const float4*)(gbf + (size_t)(rd * 32) * K + k0);
            union { __hip_bfloat162 h2[2]; uint2 u; } oa, ob;
            oa.h2[0] = __float22bfloat162_rn(make_float2(va.x, va.y));
            oa.h2[1] = __float22bfloat162_rn(make_float2(va.z, va.w));
            ob.h2[0] = __float22bfloat162_rn(make_float2(vb.x, vb.y));
            ob.h2[1] = __float22bfloat162_rn(make_float2(vb.z, vb.w));
            *(uint2*)(As + (frow + rd * 32) * 32 + fcol) = oa.u;
            *(uint2*)(Bs + (frow + rd * 32) * 32 + fcol) = ob.u;
        }
        __syncthreads();

        bf16x8 af[4], bfr[4];
#pragma unroll
        for (int i = 0; i < 4; ++i) af[i] = *(const bf16x8*)(pa + i * (16 * 32));
#pragma unroll
        for (int j = 0; j < 4; ++j) bfr[j] = *(const bf16x8*)(pb + j * (16 * 32));
#pragma unroll
        for (int i = 0; i < 4; ++i)
#pragma unroll
            for (int j = 0; j < 4; ++j)
                acc[i][j] = __builtin_amdgcn_mfma_f32_16x16x32_bf16(
                    af[i], bfr[j], acc[i][j], 0, 0, 0);
        __syncthreads();
    }

    const int cq = (lane >> 4) << 2;
    float* Cbase = C + ((size_t)bm * TM + wm + cq) * (size_t)N +
                   (size_t)bn * TN + wn + fr;
#pragma unroll
    for (int i = 0; i < 4; ++i)
#pragma unroll
        for (int r = 0; r < 4; ++r) {
            float* row = Cbase + (size_t)(16 * i + r) * N;
#pragma unroll
            for (int j = 0; j < 4; ++j) row[16 * j] = acc[i][j][r];
        }
}

extern "C" void kernel_launch(void* const* d_in, const int* in_sizes, int n_in,
                              void* d_out, int out_size, void* d_ws,
                              size_t ws_size, hipStream_t stream) {
    const float* A = (const float*)d_in[0];  // [M,K] (all_gather = reshape)
    const float* B = (const float*)d_in[1];  // [N,K]
    float* C = (float*)d_out;

    const int K = 4096;
    const int aN = in_sizes[0];
    const int bN = in_sizes[1];
    const int M = aN / K;  // 8192
    const int N = bN / K;  // 1024

    const size_t need = ((size_t)aN + (size_t)bN) * sizeof(__hip_bfloat16);

    if (ws_size >= need && (M % BM) == 0 && (N % BN) == 0) {
        __hip_bfloat16* Abf = (__hip_bfloat16*)d_ws;
        __hip_bfloat16* Bbf = Abf + (size_t)aN;
        cvt_all<<<2048, 256, 0, stream>>>(A, (uint4*)Abf, (long)(aN / 8), B,
                                          (uint4*)Bbf, (long)(bN / 8));
        dim3 grid((unsigned)((M / BM) * (N / BN)));  // 256 = 1 block/CU
        gemm_bt_pipe<<<grid, 512, 0, stream>>>((const __bf16*)Abf,
                                               (const __bf16*)Bbf, C, M, N, K);
    } else {
        dim3 grid(N / TN, M / TM);
        gemm_bt_f32in<<<grid, 256, 0, stream>>>(A, B, C, M, N, K);
    }
}